// Round 12
// baseline (142.179 us; speedup 1.0000x reference)
//
#include <hip/hip_runtime.h>

typedef short short8 __attribute__((ext_vector_type(8)));
typedef float floatx4 __attribute__((ext_vector_type(4)));
typedef unsigned uint2v __attribute__((ext_vector_type(2)));

#define INF 4096
#define TROWS 32
#define RS 528              // bf16 row stride: 512 B data + 16 B pad
#define TB (TROWS * RS)     // 16,896 B per buffer

// fp32 -> bf16 round-to-nearest-even (W prologue only)
__device__ __forceinline__ ushort f2bf(float f) {
  unsigned u = __builtin_bit_cast(unsigned, f);
  u += 0x7fffu + ((u >> 16) & 1u);
  return (ushort)(u >> 16);
}

// Block-diagonal GEMM v11 = v10 + DEPTH-2 load pipeline.
// v10 (108.5us, 78% HBM duty): staging loads issued 1 tile before their
// vmcnt-consumer (WRITEX) -- any latency stretch beyond one tile period
// (~2.7us vs ~1-2us congested latency) lands on the critical path each tile.
// v11: g[2][4] register sets, LOADX(t+2) issued at tile-t start -> every load
// gets TWO tile periods (~5us) before its WRITEX. Compiler-managed vmcnt
// (emits vmcnt(4): 4 newer loads outstanding) -- no hand counts, spill-robust.
// LDS schedule unchanged from v10 (2 bufs, 1 raw barrier + lgkmcnt(0)/tile,
// no vmcnt drains; loads cross barriers freely).
// W_k in registers (wave w owns out-cols [w*32,w*32+32): wf[2][8]).
// Swapped mfma(W, x) -> D[n][m]: lane = 4 consecutive out-cols -> dwordx4.
// Grid 256 = 16 kb x 16 mg (1024 rows = 32 tiles of 32); 512 thr, 1 WG/CU.
__global__ __launch_bounds__(512, 1) void bd_gemm(
    const float* __restrict__ x, const float* __restrict__ W,
    const float* __restrict__ bias, float* __restrict__ out)
{
  __shared__ __align__(16) char xlds[2 * TB];  // 33,792 B

  const int bid  = blockIdx.x;
  const int kb   = bid & 15;   // xcd = bid%8 -> 2 k-blocks per XCD: W L2-resident
  const int mg   = bid >> 4;   // 0..15, 1024 rows each
  const int tid  = threadIdx.x;
  const int lane = tid & 63;
  const int w    = tid >> 6;   // wave 0..7 -> out-col slice of 32
  const int ln   = lane & 15;
  const int lk   = lane >> 4;  // 0..3

  const float* xbase = x   + (size_t)(mg * 1024) * INF + kb * 256;
  float*       obase = out + (size_t)(mg * 1024) * INF + kb * 256 + w * 32;

#define LGKM0_BAR()                                                           \
  do {                                                                        \
    asm volatile("s_waitcnt lgkmcnt(0)" ::: "memory");                        \
    __builtin_amdgcn_s_barrier();                                             \
    asm volatile("" ::: "memory");                                            \
  } while (0)

  floatx4 g[2][4];  // DEPTH-2 staging: tile t lives in g[t&1] (32 VGPR)

  // one instruction = one contiguous 1 KB fp32 row -> regs
#define LOADX(t)                                                              \
  _Pragma("unroll") for (int i_ = 0; i_ < 4; ++i_)                            \
    g[(t) & 1][i_] = *(const floatx4*)(xbase + (size_t)((t) * TROWS + w * 4 + i_) * INF + lane * 4);

  // cvt ONCE to bf16, ds_write_b64: row r gets bytes [lane*8, lane*8+8)
#define WRITEX(t)                                                             \
  _Pragma("unroll") for (int i_ = 0; i_ < 4; ++i_) {                          \
    const int r_ = w * 4 + i_;                                                \
    unsigned p0_, p1_;                                                        \
    asm("v_cvt_pk_bf16_f32 %0, %1, %2" : "=v"(p0_) : "v"(g[(t) & 1][i_][0]), "v"(g[(t) & 1][i_][1])); \
    asm("v_cvt_pk_bf16_f32 %0, %1, %2" : "=v"(p1_) : "v"(g[(t) & 1][i_][2]), "v"(g[(t) & 1][i_][3])); \
    uint2v u_; u_[0] = p0_; u_[1] = p1_;                                      \
    *(uint2v*)(xlds + ((t) & 1) * TB + r_ * RS + lane * 8) = u_;              \
  }

  // 16 ds_read_b128 + 32 MFMA per tile per wave (frag: x[mi*16+ln][kc*32+lk*8+e])
#define COMPUTE(t)                                                            \
  {                                                                           \
    const char* bb_ = xlds + ((t) & 1) * TB;                                  \
    _Pragma("unroll") for (int a_ = 0; a_ < 4; ++a_)                          \
      _Pragma("unroll") for (int e_ = 0; e_ < 4; ++e_) acc[a_][e_] = 0.0f;    \
    _Pragma("unroll") for (int kc_ = 0; kc_ < 8; ++kc_) {                     \
      short8 xf_[2];                                                          \
      _Pragma("unroll") for (int mi_ = 0; mi_ < 2; ++mi_)                     \
        xf_[mi_] = *(const short8*)(bb_ + (mi_ * 16 + ln) * RS + kc_ * 64 + lk * 16); \
      _Pragma("unroll") for (int mi_ = 0; mi_ < 2; ++mi_)                     \
        _Pragma("unroll") for (int ni_ = 0; ni_ < 2; ++ni_)                   \
          acc[mi_ * 2 + ni_] = __builtin_amdgcn_mfma_f32_16x16x32_bf16(       \
              wf[ni_][kc_], xf_[mi_], acc[mi_ * 2 + ni_], 0, 0, 0);           \
    }                                                                         \
  }

  // frag D[n][m]: m(row) = mi*16 + ln, n(col) = ni*16 + lk*4 + j -> dwordx4
#define STOREACC(t)                                                           \
  _Pragma("unroll") for (int mi_ = 0; mi_ < 2; ++mi_)                         \
    _Pragma("unroll") for (int ni_ = 0; ni_ < 2; ++ni_) {                     \
      floatx4 r_ = acc[mi_ * 2 + ni_];                                        \
      _Pragma("unroll") for (int j_ = 0; j_ < 4; ++j_) r_[j_] += bv[ni_][j_]; \
      *(floatx4*)(obase + (size_t)((t) * TROWS + mi_ * 16 + ln) * INF +       \
                  ni_ * 16 + lk * 4) = r_;                                    \
    }

  // ---- prologue: tiles 0,1 loads first, W frags under their latency ----
  LOADX(0)
  LOADX(1)

  short8 wf[2][8];  // wave w cols [w*32, w*32+32): A-layout [row=n (ln)][k=lk*8+e]
  {
    const float* wp = W + (size_t)kb * 65536 + (w * 32 + ln) * 256 + lk * 8;
#pragma unroll
    for (int ni = 0; ni < 2; ++ni)
#pragma unroll
      for (int kc = 0; kc < 8; ++kc) {
        const float* s = wp + ni * 16 * 256 + kc * 32;
        floatx4 v0 = *(const floatx4*)s;
        floatx4 v1 = *(const floatx4*)(s + 4);
        short8 u;
#pragma unroll
        for (int j = 0; j < 4; ++j) {
          u[j]     = (short)f2bf(v0[j]);
          u[4 + j] = (short)f2bf(v1[j]);
        }
        wf[ni][kc] = u;
      }
  }
  floatx4 bv[2];
#pragma unroll
  for (int ni = 0; ni < 2; ++ni)
    bv[ni] = *(const floatx4*)(bias + kb * 256 + w * 32 + ni * 16 + lk * 4);

  floatx4 acc[4];

  WRITEX(0)        // compiler vmcnt wait: only tile-0's 4 loads must land
  LGKM0_BAR();

  // ---- main loop: 32 tiles; loads issued 2 tiles ahead, 1 barrier/tile ----
#pragma unroll 1
  for (int t = 0; t < 32; ++t) {
    if (t < 30) LOADX(t + 2)   // 2 tile periods before WRITEX(t+2) consumes
    COMPUTE(t)
    STOREACC(t)
    if (t < 31) {
      WRITEX(t + 1)            // compiler emits vmcnt(4): t+2's loads newer
      LGKM0_BAR();             // ds_writes visible; NO vmcnt drain
    }
  }

#undef LGKM0_BAR
#undef LOADX
#undef WRITEX
#undef COMPUTE
#undef STOREACC
}

extern "C" void kernel_launch(void* const* d_in, const int* in_sizes, int n_in,
                              void* d_out, int out_size, void* d_ws, size_t ws_size,
                              hipStream_t stream) {
  const float* x = (const float*)d_in[0];
  const float* W = (const float*)d_in[1];
  const float* b = (const float*)d_in[2];
  float* out = (float*)d_out;
  // 16 k-blocks x 16 m-groups = 256 WGs (1/CU), 512 threads (8 waves)
  hipLaunchKernelGGL(bd_gemm, dim3(256), dim3(512), 0, stream, x, W, b, out);
}

// Round 13
// 115.231 us; speedup vs baseline: 1.2339x; 1.2339x over previous
//
#include <hip/hip_runtime.h>

typedef short short8 __attribute__((ext_vector_type(8)));
typedef float floatx4 __attribute__((ext_vector_type(4)));
typedef unsigned uint2v __attribute__((ext_vector_type(2)));

#define INF 4096
#define TROWS 32
#define RS 528              // bf16 row stride: 512 B data + 16 B pad
#define TB (TROWS * RS)     // 16,896 B per buffer

// fp32 -> bf16 round-to-nearest-even (W prologue only)
__device__ __forceinline__ ushort f2bf(float f) {
  unsigned u = __builtin_bit_cast(unsigned, f);
  u += 0x7fffu + ((u >> 16) & 1u);
  return (ushort)(u >> 16);
}

// Block-diagonal GEMM v13 = v10 + depth-2 load pipeline with STATIC reg sets.
// v11/v12's g[(t)&1] was a rule-#20 violation (runtime-indexed register array
// -> compiler pathology, 142us). v13 pair-unrolls the loop so the two staging
// sets are named gA/gB with compile-time indexing:
//   pair p: LOADX(gA,t0+2); COMPUTE(t0); WRITEX(gB,t1); BAR;
//           LOADX(gB,t1+2); COMPUTE(t1); WRITEX(gA,t0+2); BAR;
// -> every staging load has TWO full COMPUTE periods (~4000 cyc) before its
// WRITEX consumer (v10: ~1 period, marginal vs congested HBM latency).
// All other structure = v10 (108.5us): bf16-in-LDS cvt-once, 2 LDS bufs,
// 1 raw s_barrier + lgkmcnt(0) per tile, NO vmcnt drains, compiler-managed
// vmcnt (spill-robust), W_k in regs, swapped mfma(W,x)->D[n][m], dwordx4 IO.
// Grid 256 = 16 kb x 16 mg (1024 rows = 32 tiles of 32); 512 thr, 1 WG/CU.
__global__ __launch_bounds__(512, 1) void bd_gemm(
    const float* __restrict__ x, const float* __restrict__ W,
    const float* __restrict__ bias, float* __restrict__ out)
{
  __shared__ __align__(16) char xlds[2 * TB];  // 33,792 B

  const int bid  = blockIdx.x;
  const int kb   = bid & 15;   // xcd = bid%8 -> 2 k-blocks per XCD: W L2-resident
  const int mg   = bid >> 4;   // 0..15, 1024 rows each
  const int tid  = threadIdx.x;
  const int lane = tid & 63;
  const int w    = tid >> 6;   // wave 0..7 -> out-col slice of 32
  const int ln   = lane & 15;
  const int lk   = lane >> 4;  // 0..3

  const float* xbase = x   + (size_t)(mg * 1024) * INF + kb * 256;
  float*       obase = out + (size_t)(mg * 1024) * INF + kb * 256 + w * 32;

#define LGKM0_BAR()                                                           \
  do {                                                                        \
    asm volatile("s_waitcnt lgkmcnt(0)" ::: "memory");                        \
    __builtin_amdgcn_s_barrier();                                             \
    asm volatile("" ::: "memory");                                            \
  } while (0)

  floatx4 gA[4], gB[4];  // two STATIC staging sets (16 VGPR each)

  // one instruction = one contiguous 1 KB fp32 row -> regs
#define LOADX(gs, t)                                                          \
  _Pragma("unroll") for (int i_ = 0; i_ < 4; ++i_)                            \
    gs[i_] = *(const floatx4*)(xbase + (size_t)((t) * TROWS + w * 4 + i_) * INF + lane * 4);

  // cvt ONCE to bf16, ds_write_b64: row r gets bytes [lane*8, lane*8+8)
#define WRITEX(gs, t)                                                         \
  _Pragma("unroll") for (int i_ = 0; i_ < 4; ++i_) {                          \
    const int r_ = w * 4 + i_;                                                \
    unsigned p0_, p1_;                                                        \
    asm("v_cvt_pk_bf16_f32 %0, %1, %2" : "=v"(p0_) : "v"(gs[i_][0]), "v"(gs[i_][1])); \
    asm("v_cvt_pk_bf16_f32 %0, %1, %2" : "=v"(p1_) : "v"(gs[i_][2]), "v"(gs[i_][3])); \
    uint2v u_; u_[0] = p0_; u_[1] = p1_;                                      \
    *(uint2v*)(xlds + ((t) & 1) * TB + r_ * RS + lane * 8) = u_;              \
  }

  // 16 ds_read_b128 + 32 MFMA per tile per wave (frag: x[mi*16+ln][kc*32+lk*8+e])
#define COMPUTE(t)                                                            \
  {                                                                           \
    const char* bb_ = xlds + ((t) & 1) * TB;                                  \
    _Pragma("unroll") for (int a_ = 0; a_ < 4; ++a_)                          \
      _Pragma("unroll") for (int e_ = 0; e_ < 4; ++e_) acc[a_][e_] = 0.0f;    \
    _Pragma("unroll") for (int kc_ = 0; kc_ < 8; ++kc_) {                     \
      short8 xf_[2];                                                          \
      _Pragma("unroll") for (int mi_ = 0; mi_ < 2; ++mi_)                     \
        xf_[mi_] = *(const short8*)(bb_ + (mi_ * 16 + ln) * RS + kc_ * 64 + lk * 16); \
      _Pragma("unroll") for (int mi_ = 0; mi_ < 2; ++mi_)                     \
        _Pragma("unroll") for (int ni_ = 0; ni_ < 2; ++ni_)                   \
          acc[mi_ * 2 + ni_] = __builtin_amdgcn_mfma_f32_16x16x32_bf16(       \
              wf[ni_][kc_], xf_[mi_], acc[mi_ * 2 + ni_], 0, 0, 0);           \
    }                                                                         \
  }

  // frag D[n][m]: m(row) = mi*16 + ln, n(col) = ni*16 + lk*4 + j -> dwordx4
#define STOREACC(t)                                                           \
  _Pragma("unroll") for (int mi_ = 0; mi_ < 2; ++mi_)                         \
    _Pragma("unroll") for (int ni_ = 0; ni_ < 2; ++ni_) {                     \
      floatx4 r_ = acc[mi_ * 2 + ni_];                                        \
      _Pragma("unroll") for (int j_ = 0; j_ < 4; ++j_) r_[j_] += bv[ni_][j_]; \
      *(floatx4*)(obase + (size_t)((t) * TROWS + mi_ * 16 + ln) * INF +       \
                  ni_ * 16 + lk * 4) = r_;                                    \
    }

  // ---- prologue: tiles 0,1 loads first, W frags under their latency ----
  LOADX(gA, 0)
  LOADX(gB, 1)

  short8 wf[2][8];  // wave w cols [w*32, w*32+32): A-layout [row=n (ln)][k=lk*8+e]
  {
    const float* wp = W + (size_t)kb * 65536 + (w * 32 + ln) * 256 + lk * 8;
#pragma unroll
    for (int ni = 0; ni < 2; ++ni)
#pragma unroll
      for (int kc = 0; kc < 8; ++kc) {
        const float* s = wp + ni * 16 * 256 + kc * 32;
        floatx4 v0 = *(const floatx4*)s;
        floatx4 v1 = *(const floatx4*)(s + 4);
        short8 u;
#pragma unroll
        for (int j = 0; j < 4; ++j) {
          u[j]     = (short)f2bf(v0[j]);
          u[4 + j] = (short)f2bf(v1[j]);
        }
        wf[ni][kc] = u;
      }
  }
  floatx4 bv[2];
#pragma unroll
  for (int ni = 0; ni < 2; ++ni)
    bv[ni] = *(const floatx4*)(bias + kb * 256 + w * 32 + ni * 16 + lk * 4);

  floatx4 acc[4];

  WRITEX(gA, 0)    // consumes gA (tile 0); compiler vmcnt wait lands here
  LGKM0_BAR();

  // ---- main loop: 16 pairs = 32 tiles; static gA=even / gB=odd tiles ----
#pragma unroll 1
  for (int p = 0; p < 16; ++p) {
    const int t0 = 2 * p, t1 = 2 * p + 1;
    if (t0 + 2 < 32) LOADX(gA, t0 + 2)     // 2 COMPUTEs before WRITEX(gA,t0+2)
    COMPUTE(t0)
    STOREACC(t0)
    WRITEX(gB, t1)                          // gB loaded 2 COMPUTEs ago
    LGKM0_BAR();
    if (t1 + 2 < 32) LOADX(gB, t1 + 2)     // 2 COMPUTEs before next pair's WRITEX
    COMPUTE(t1)
    STOREACC(t1)
    if (t0 + 2 < 32) {
      WRITEX(gA, t0 + 2)                    // gA loaded at top of this pair
      LGKM0_BAR();
    }
  }

#undef LGKM0_BAR
#undef LOADX
#undef WRITEX
#undef COMPUTE
#undef STOREACC
}

extern "C" void kernel_launch(void* const* d_in, const int* in_sizes, int n_in,
                              void* d_out, int out_size, void* d_ws, size_t ws_size,
                              hipStream_t stream) {
  const float* x = (const float*)d_in[0];
  const float* W = (const float*)d_in[1];
  const float* b = (const float*)d_in[2];
  float* out = (float*)d_out;
  // 16 k-blocks x 16 m-groups = 256 WGs (1/CU), 512 threads (8 waves)
  hipLaunchKernelGGL(bd_gemm, dim3(256), dim3(512), 0, stream, x, W, b, out);
}